// Round 16
// baseline (108.869 us; speedup 1.0000x reference)
//
#include <hip/hip_runtime.h>

#define N_NODES 50000
#define E_EDGES 1600000
#define ETOT    (E_EDGES + N_NODES)
#define DIN  128
#define DOUT 128
#define NH   4
#define HD   32

typedef unsigned short ushort_t;
typedef unsigned int uint_t;
typedef __attribute__((ext_vector_type(8))) short bfrag;   // 8 bf16 (4 VGPRs)
typedef __attribute__((ext_vector_type(4))) float ffrag;   // 4 fp32 acc

__device__ __forceinline__ ushort_t f2bf(float f) {
  uint_t u = __float_as_uint(f);
  u += 0x7fffu + ((u >> 16) & 1u);   // RNE
  return (ushort_t)(u >> 16);
}
__device__ __forceinline__ float bf_lo(uint_t u) {
  return __uint_as_float(u << 16);
}
__device__ __forceinline__ float bf_hi(uint_t u) {
  return __uint_as_float(u & 0xffff0000u);
}

// ---------------- CSR build params ----------------
#define BSZ   64
#define NBUCK ((N_NODES + BSZ - 1) / BSZ)       // 782
#define CAP   2560                               // per-bucket capacity (mean 2112)
#define EPB_A 8192
#define NBLK_A ((ETOT + EPB_A - 1) / EPB_A)     // 202
#define NCHUNK 13                                // src chunk = si>>12 (0..12)
#define GEMM_BLOCKS ((N_NODES + 63) / 64)       // 782

// ---------------- K1: role-split fused kernel ----------------
// blocks [0, GEMM_BLOCKS): cast+GEMM(MFMA)+att-logits (r15 proven body)
// blocks [GEMM_BLOCKS, +NBLK_A): countA — per-block bucket histogram,
//   PLAIN writes to cnt matrix (no global atomics at all).
__global__ __launch_bounds__(256, 4) void fused_gemm_count_kernel(
    const float* __restrict__ x, const float* __restrict__ W,
    const float* __restrict__ att_src, const float* __restrict__ att_dst,
    ushort_t* __restrict__ hb, float* __restrict__ a_src,
    float* __restrict__ a_dst,
    const int* __restrict__ ei, int* __restrict__ cnt) {
  __shared__ ushort_t Ws[DIN * DOUT];   // 32 KB; countA role aliases as int[]
  const int tid = threadIdx.x;

  if (blockIdx.x >= GEMM_BLOCKS) {
    // ---------- countA role ----------
    int* hist = (int*)Ws;              // [NBUCK], 3.1 KB of the 32 KB
    const int cb = blockIdx.x - GEMM_BLOCKS;
    const int e0 = cb * EPB_A;
    const int e1 = min(e0 + EPB_A, ETOT);
    for (int i = tid; i < NBUCK; i += 256) hist[i] = 0;
    __syncthreads();
    for (int e = e0 + tid; e < e1; e += 256) {
      int di = (e < E_EDGES) ? ei[E_EDGES + e] : (e - E_EDGES);
      atomicAdd(&hist[di >> 6], 1);
    }
    __syncthreads();
    for (int i = tid; i < NBUCK; i += 256)
      cnt[(size_t)cb * NBUCK + i] = hist[i];   // coalesced, no atomics
    return;
  }

  // ---------- gemm_att role (r15 proven) ----------
  const int gb = blockIdx.x;
  const int wv = tid >> 6, l = tid & 63;
  const int lr = l & 15, lg = l >> 4;
  const int nbase = gb * 64 + wv * 16;
  int na = nbase + lr;
  if (na >= N_NODES) na = N_NODES - 1;
  const float* xrow = x + (size_t)na * DIN;

  float4 px[8];
#pragma unroll
  for (int kt = 0; kt < 4; kt++) {
    px[kt * 2]     = *(const float4*)&xrow[kt * 32 + lg * 8];
    px[kt * 2 + 1] = *(const float4*)&xrow[kt * 32 + lg * 8 + 4];
  }

  for (int u = tid; u < 2048; u += 256) {
    int row = u >> 4;
    float4 w0 = *(const float4*)&W[u * 8];
    float4 w1 = *(const float4*)&W[u * 8 + 4];
    uint4 pk;
    pk.x = (uint_t)f2bf(w0.x) | ((uint_t)f2bf(w0.y) << 16);
    pk.y = (uint_t)f2bf(w0.z) | ((uint_t)f2bf(w0.w) << 16);
    pk.z = (uint_t)f2bf(w1.x) | ((uint_t)f2bf(w1.y) << 16);
    pk.w = (uint_t)f2bf(w1.z) | ((uint_t)f2bf(w1.w) << 16);
    *(uint4*)&Ws[(u ^ (row & 7)) * 8] = pk;
  }
  __syncthreads();

  ffrag acc[8];
#pragma unroll
  for (int oc = 0; oc < 8; oc++) acc[oc] = (ffrag){0.f, 0.f, 0.f, 0.f};

#pragma unroll
  for (int kt = 0; kt < 4; kt++) {
    const float4 x0 = px[kt * 2];
    const float4 x1 = px[kt * 2 + 1];
    bfrag a;
    a[0] = (short)f2bf(x0.x); a[1] = (short)f2bf(x0.y);
    a[2] = (short)f2bf(x0.z); a[3] = (short)f2bf(x0.w);
    a[4] = (short)f2bf(x1.x); a[5] = (short)f2bf(x1.y);
    a[6] = (short)f2bf(x1.z); a[7] = (short)f2bf(x1.w);
#pragma unroll
    for (int oc = 0; oc < 8; oc++) {
      const int u = ((oc * 16 + lr) << 4) + kt * 4 + lg;
      const bfrag b = *(const bfrag*)&Ws[(u ^ (lr & 7)) * 8];
      acc[oc] = __builtin_amdgcn_mfma_f32_16x16x32_bf16(a, b, acc[oc], 0, 0, 0);
    }
  }

#pragma unroll
  for (int oc = 0; oc < 8; oc++) {
#pragma unroll
    for (int j = 0; j < 4; j++) {
      int n = nbase + lg * 4 + j;
      if (n < N_NODES)
        hb[((size_t)n << 7) + oc * 16 + lr] = f2bf(acc[oc][j]);
    }
  }

  float asv[8], adv[8];
#pragma unroll
  for (int oc = 0; oc < 8; oc++) {
    asv[oc] = att_src[oc * 16 + lr];
    adv[oc] = att_dst[oc * 16 + lr];
  }
#pragma unroll
  for (int j = 0; j < 4; j++) {
    float ps[4] = {0.f, 0.f, 0.f, 0.f};
    float pd[4] = {0.f, 0.f, 0.f, 0.f};
#pragma unroll
    for (int oc = 0; oc < 8; oc++) {
      ps[oc >> 1] = fmaf(acc[oc][j], asv[oc], ps[oc >> 1]);
      pd[oc >> 1] = fmaf(acc[oc][j], adv[oc], pd[oc >> 1]);
    }
#pragma unroll
    for (int off = 1; off < 16; off <<= 1) {
#pragma unroll
      for (int hd = 0; hd < 4; hd++) {
        ps[hd] += __shfl_xor(ps[hd], off);
        pd[hd] += __shfl_xor(pd[hd], off);
      }
    }
    int n = nbase + lg * 4 + j;
    if (n < N_NODES && lr < 4) {
      float vs = lr == 0 ? ps[0] : lr == 1 ? ps[1] : lr == 2 ? ps[2] : ps[3];
      float vd = lr == 0 ? pd[0] : lr == 1 ? pd[1] : lr == 2 ? pd[2] : pd[3];
      a_src[n * NH + lr] = vs;
      a_dst[n * NH + lr] = vd;
    }
  }
}

// ---------------- K2: per-bucket column scan (one wave per bucket) --------
// cnt[blk][b] -> absolute base b*CAP + excl-prefix over blk; btot[b] = total.
__global__ __launch_bounds__(64) void bscan_kernel(
    int* __restrict__ cnt, int* __restrict__ btot) {
  const int b = blockIdx.x;
  const int lane = threadIdx.x;
  const int blk = lane * 4;   // 64 lanes x 4 = 256 >= NBLK_A
  int v0 = 0, v1 = 0, v2 = 0, v3 = 0;
  if (blk     < NBLK_A) v0 = cnt[(size_t)blk * NBUCK + b];
  if (blk + 1 < NBLK_A) v1 = cnt[(size_t)(blk + 1) * NBUCK + b];
  if (blk + 2 < NBLK_A) v2 = cnt[(size_t)(blk + 2) * NBUCK + b];
  if (blk + 3 < NBLK_A) v3 = cnt[(size_t)(blk + 3) * NBUCK + b];
  const int p1 = v0, p2 = v0 + v1, p3 = v0 + v1 + v2;
  const int s = v0 + v1 + v2 + v3;
  int xx = s;
#pragma unroll
  for (int off = 1; off < 64; off <<= 1) {
    int y = __shfl_up(xx, off, 64);
    if (lane >= off) xx += y;
  }
  const int base = b * CAP + (xx - s);   // exclusive prefix
  if (blk     < NBLK_A) cnt[(size_t)blk * NBUCK + b]       = base;
  if (blk + 1 < NBLK_A) cnt[(size_t)(blk + 1) * NBUCK + b] = base + p1;
  if (blk + 2 < NBLK_A) cnt[(size_t)(blk + 2) * NBUCK + b] = base + p2;
  if (blk + 3 < NBLK_A) cnt[(size_t)(blk + 3) * NBUCK + b] = base + p3;
  if (lane == 63) btot[b] = xx;   // inclusive total of bucket b
}

// ---------------- K3: place edges at exact positions (no global atomics) --
__global__ __launch_bounds__(256) void place_kernel(
    const int* __restrict__ ei, const int* __restrict__ cnt,
    uint_t* __restrict__ ebuf) {
  __shared__ int base[NBUCK];
  __shared__ int hist[NBUCK];
  const int cb = blockIdx.x;
  const int tid = threadIdx.x;
  for (int i = tid; i < NBUCK; i += 256) {
    base[i] = cnt[(size_t)cb * NBUCK + i];
    hist[i] = 0;
  }
  __syncthreads();
  const int e0 = cb * EPB_A;
  const int e1 = min(e0 + EPB_A, ETOT);
  for (int e = e0 + tid; e < e1; e += 256) {
    int si, di;
    if (e < E_EDGES) { si = ei[e]; di = ei[E_EDGES + e]; }
    else             { si = e - E_EDGES; di = si; }
    int b = di >> 6;
    int pos = base[b] + atomicAdd(&hist[b], 1);
    if (pos < (b + 1) * CAP)   // capacity guard: drop -> absmax catches
      ebuf[pos] = ((uint_t)(di & 63) << 24) | (uint_t)si;
  }
}

// ---------------- K4: per-bucket CSR build (r13 proven; btot) ----------
__global__ __launch_bounds__(256) void binB_kernel(
    const uint_t* __restrict__ ebuf, const int* __restrict__ btot,
    int* __restrict__ rs, int* __restrict__ re, int* __restrict__ col) {
  __shared__ int cnt_l[BSZ * NCHUNK];    // 3.3 KB
  __shared__ int roff[BSZ * NCHUNK];
  const int b = blockIdx.x;
  const int tid = threadIdx.x;
  const int n0 = b << 6;
  const int nn = min(BSZ, N_NODES - n0);
  const int s0 = b * CAP;
  const int s1 = s0 + min(btot[b], CAP);
  for (int k = tid; k < BSZ * NCHUNK; k += 256) cnt_l[k] = 0;
  __syncthreads();
  for (int i = s0 + tid; i < s1; i += 256) {
    uint_t p = ebuf[i];
    int key = (int)(p >> 24) * NCHUNK + (int)((p & 0xFFFFFFu) >> 12);
    atomicAdd(&cnt_l[key], 1);
  }
  __syncthreads();
  if (tid < BSZ) {   // one wave: node = tid
    int pref[NCHUNK];
    int tot = 0;
#pragma unroll
    for (int k = 0; k < NCHUNK; k++) { pref[k] = tot; tot += cnt_l[tid * NCHUNK + k]; }
    int xx = tot;
#pragma unroll
    for (int off = 1; off < 64; off <<= 1) {
      int y = __shfl_up(xx, off, 64);
      if (tid >= off) xx += y;
    }
    const int nodebase = xx - tot;   // exclusive
#pragma unroll
    for (int k = 0; k < NCHUNK; k++) roff[tid * NCHUNK + k] = nodebase + pref[k];
    if (tid < nn) {
      rs[n0 + tid] = s0 + nodebase;
      re[n0 + tid] = s0 + nodebase + tot;
    }
  }
  __syncthreads();
  for (int k = tid; k < BSZ * NCHUNK; k += 256) cnt_l[k] = 0;
  __syncthreads();
  for (int i = s0 + tid; i < s1; i += 256) {
    uint_t p = ebuf[i];
    int si = (int)(p & 0xFFFFFFu);
    int key = (int)(p >> 24) * NCHUNK + (si >> 12);
    int pos = atomicAdd(&cnt_l[key], 1);
    int q = s0 + roff[key] + pos;
    if (q >= 0 && q < NBUCK * CAP) col[q] = si;
  }
}

// ---------------- K5: SINGLE-PASS aggregation (r13 proven) ----------------
// out = (sum e_i*h_i)/s + sum h_i,  e_i = exp(leaky(alpha_i)), s = sum e_i.
#define NPB 16
#define CH  16

__global__ __launch_bounds__(256, 8) void agg_kernel(
    const int* __restrict__ col, const int* __restrict__ rs,
    const int* __restrict__ re, const ushort_t* __restrict__ hb,
    const float* __restrict__ a_src, const float* __restrict__ a_dst,
    float* __restrict__ out) {
  __shared__ float w_lds[NPB][CH][NH];   // 4 KB (unnormalized e)
  __shared__ int   si_lds[NPB][CH];      // 1 KB
  const int tid  = threadIdx.x;
  const int slot = tid >> 4;
  const int t    = tid & 15;
  const int node = blockIdx.x * NPB + slot;   // 3125*16 == N_NODES exactly
  const int start = rs[node];
  const int deg   = re[node] - start;
  const float4 ad = *(const float4*)(a_dst + (size_t)node * NH);

  const int head = t >> 2;
  const int c8 = t << 3;
  const ushort_t* hc = hb + c8;
  float s = 0.f;
  float a0 = 0.f, a1 = 0.f, a2 = 0.f, a3 = 0.f;
  float a4 = 0.f, a5 = 0.f, a6 = 0.f, a7 = 0.f;
  float b0 = 0.f, b1 = 0.f, b2 = 0.f, b3 = 0.f;
  float b4 = 0.f, b5 = 0.f, b6 = 0.f, b7 = 0.f;

  for (int base_e = 0; base_e < deg; base_e += CH) {
    int nch = deg - base_e;
    if (nch > CH) nch = CH;
    if (t < nch) {
      int si = col[start + base_e + t];
      si = si < N_NODES ? si : 0;    // defensive clamp
      si_lds[slot][t] = si;
      float4 as = *(const float4*)(a_src + (size_t)si * NH);
      float v0 = as.x + ad.x; v0 = v0 > 0.f ? v0 : 0.2f * v0;
      float v1 = as.y + ad.y; v1 = v1 > 0.f ? v1 : 0.2f * v1;
      float v2 = as.z + ad.z; v2 = v2 > 0.f ? v2 : 0.2f * v2;
      float v3 = as.w + ad.w; v3 = v3 > 0.f ? v3 : 0.2f * v3;
      w_lds[slot][t][0] = __expf(v0);
      w_lds[slot][t][1] = __expf(v1);
      w_lds[slot][t][2] = __expf(v2);
      w_lds[slot][t][3] = __expf(v3);
    }
    __builtin_amdgcn_fence(__ATOMIC_ACQ_REL, "wavefront");
#pragma unroll 2
    for (int j = 0; j < nch; j++) {
      int si = si_lds[slot][j];
      float e = w_lds[slot][j][head];
      s += e;
      const uint4 hv = *(const uint4*)(hc + ((size_t)si << 7));
      float h0 = bf_lo(hv.x), h1 = bf_hi(hv.x);
      float h2 = bf_lo(hv.y), h3 = bf_hi(hv.y);
      float h4 = bf_lo(hv.z), h5 = bf_hi(hv.z);
      float h6 = bf_lo(hv.w), h7 = bf_hi(hv.w);
      a0 = fmaf(h0, e, a0); b0 += h0;
      a1 = fmaf(h1, e, a1); b1 += h1;
      a2 = fmaf(h2, e, a2); b2 += h2;
      a3 = fmaf(h3, e, a3); b3 += h3;
      a4 = fmaf(h4, e, a4); b4 += h4;
      a5 = fmaf(h5, e, a5); b5 += h5;
      a6 = fmaf(h6, e, a6); b6 += h6;
      a7 = fmaf(h7, e, a7); b7 += h7;
    }
    __builtin_amdgcn_fence(__ATOMIC_ACQ_REL, "wavefront");
  }
  const float inv = 1.0f / s;
  float* op = out + ((size_t)node << 7) + c8;
  *(float4*)(op)     = make_float4(fmaf(a0, inv, b0), fmaf(a1, inv, b1),
                                   fmaf(a2, inv, b2), fmaf(a3, inv, b3));
  *(float4*)(op + 4) = make_float4(fmaf(a4, inv, b4), fmaf(a5, inv, b5),
                                   fmaf(a6, inv, b6), fmaf(a7, inv, b7));
}

extern "C" void kernel_launch(void* const* d_in, const int* in_sizes, int n_in,
                              void* d_out, int out_size, void* d_ws, size_t ws_size,
                              hipStream_t stream) {
  const float* x       = (const float*)d_in[0];
  const int*   ei      = (const int*)d_in[1];
  const float* W       = (const float*)d_in[2];
  const float* att_src = (const float*)d_in[3];
  const float* att_dst = (const float*)d_in[4];
  float* out = (float*)d_out;

  // ws: hb | a_src | a_dst | cnt(NBLK_A*NBUCK) | btot | rs | re | col | ebuf
  ushort_t* hb = (ushort_t*)d_ws;
  float* a_src = (float*)(hb + (size_t)N_NODES * DOUT);
  float* a_dst = a_src + (size_t)N_NODES * NH;
  int* cnt     = (int*)(a_dst + (size_t)N_NODES * NH);    // NBLK_A*NBUCK
  int* btot    = cnt + (size_t)NBLK_A * NBUCK;            // NBUCK
  int* rs      = btot + NBUCK;                            // N_NODES
  int* re      = rs + N_NODES;                            // N_NODES
  int* col     = re + N_NODES;                            // NBUCK*CAP
  uint_t* ebuf = (uint_t*)(col + (size_t)NBUCK * CAP);    // NBUCK*CAP

  fused_gemm_count_kernel<<<GEMM_BLOCKS + NBLK_A, 256, 0, stream>>>(
      x, W, att_src, att_dst, hb, a_src, a_dst, ei, cnt);
  bscan_kernel<<<NBUCK, 64, 0, stream>>>(cnt, btot);
  place_kernel<<<NBLK_A, 256, 0, stream>>>(ei, cnt, ebuf);
  binB_kernel<<<NBUCK, 256, 0, stream>>>(ebuf, btot, rs, re, col);
  agg_kernel<<<N_NODES / NPB, 256, 0, stream>>>(col, rs, re, hb, a_src, a_dst, out);
}

// Round 17
// 105.305 us; speedup vs baseline: 1.0338x; 1.0338x over previous
//
#include <hip/hip_runtime.h>

#define N_NODES 50000
#define E_EDGES 1600000
#define ETOT    (E_EDGES + N_NODES)
#define DIN  128
#define DOUT 128
#define NH   4
#define HD   32

typedef unsigned short ushort_t;
typedef unsigned int uint_t;
typedef __attribute__((ext_vector_type(8))) short bfrag;   // 8 bf16 (4 VGPRs)
typedef __attribute__((ext_vector_type(4))) float ffrag;   // 4 fp32 acc

__device__ __forceinline__ ushort_t f2bf(float f) {
  uint_t u = __float_as_uint(f);
  u += 0x7fffu + ((u >> 16) & 1u);   // RNE
  return (ushort_t)(u >> 16);
}
__device__ __forceinline__ float bf_lo(uint_t u) {
  return __uint_as_float(u << 16);
}
__device__ __forceinline__ float bf_hi(uint_t u) {
  return __uint_as_float(u & 0xffff0000u);
}

// ---------------- CSR build params ----------------
#define BSZ   64
#define NBUCK ((N_NODES + BSZ - 1) / BSZ)       // 782
#define CAP   2560                               // per-bucket capacity (mean 2112)
#define EPB_A 4096
#define NBLK_A ((ETOT + EPB_A - 1) / EPB_A)     // 403
#define NCHUNK 13                                // src chunk = si>>12 (0..12)
#define RPS   132                                // repack row stride (ushorts)

// ---------------- K1: role-split fused kernel (32 KB LDS, overlaid) -------
__global__ __launch_bounds__(256, 4) void fused_binA_gemm_kernel(
    const int* __restrict__ ei, int* __restrict__ gcur,
    uint_t* __restrict__ ebuf,
    const float* __restrict__ x, const float* __restrict__ W,
    const float* __restrict__ att_src, const float* __restrict__ att_dst,
    ushort_t* __restrict__ hb, float* __restrict__ a_src,
    float* __restrict__ a_dst) {
  __shared__ ushort_t Ws[DIN * DOUT];   // 32 KB; binA aliases; repack reuses
  const int tid = threadIdx.x;

  if (blockIdx.x < NBLK_A) {
    // ---------- binA role (hist/base overlaid on Ws) ----------
    int* hist = (int*)Ws;          // [NBUCK]
    int* base = hist + NBUCK;      // [NBUCK]
    const int e0 = blockIdx.x * EPB_A;
    const int e1 = min(e0 + EPB_A, ETOT);
    for (int i = tid; i < NBUCK; i += 256) hist[i] = 0;
    __syncthreads();
    for (int e = e0 + tid; e < e1; e += 256) {
      int di = (e < E_EDGES) ? ei[E_EDGES + e] : (e - E_EDGES);
      atomicAdd(&hist[di >> 6], 1);
    }
    __syncthreads();
    for (int i = tid; i < NBUCK; i += 256) {
      int c = hist[i];
      base[i] = (c > 0) ? (i * CAP + atomicAdd(&gcur[i], c)) : 0;
      hist[i] = 0;
    }
    __syncthreads();
    for (int e = e0 + tid; e < e1; e += 256) {
      int si, di;
      if (e < E_EDGES) { si = ei[e]; di = ei[E_EDGES + e]; }
      else             { si = e - E_EDGES; di = si; }
      int b = di >> 6;
      int pos = base[b] + atomicAdd(&hist[b], 1);
      if (pos < (b + 1) * CAP)   // capacity guard: drop -> absmax catches
        ebuf[pos] = ((uint_t)(di & 63) << 24) | (uint_t)si;
    }
    return;
  }

  // ---------- gemm_att role ----------
  const int gb = blockIdx.x - NBLK_A;
  const int wv = tid >> 6, l = tid & 63;
  const int lr = l & 15, lg = l >> 4;
  const int nbase = gb * 64 + wv * 16;
  int na = nbase + lr;
  if (na >= N_NODES) na = N_NODES - 1;
  const float* xrow = x + (size_t)na * DIN;

  // prefetch x chunks: HBM latency overlaps W staging + barrier
  float4 px[8];
#pragma unroll
  for (int kt = 0; kt < 4; kt++) {
    px[kt * 2]     = *(const float4*)&xrow[kt * 32 + lg * 8];
    px[kt * 2 + 1] = *(const float4*)&xrow[kt * 32 + lg * 8 + 4];
  }

  for (int u = tid; u < 2048; u += 256) {
    int row = u >> 4;
    float4 w0 = *(const float4*)&W[u * 8];
    float4 w1 = *(const float4*)&W[u * 8 + 4];
    uint4 pk;
    pk.x = (uint_t)f2bf(w0.x) | ((uint_t)f2bf(w0.y) << 16);
    pk.y = (uint_t)f2bf(w0.z) | ((uint_t)f2bf(w0.w) << 16);
    pk.z = (uint_t)f2bf(w1.x) | ((uint_t)f2bf(w1.y) << 16);
    pk.w = (uint_t)f2bf(w1.z) | ((uint_t)f2bf(w1.w) << 16);
    *(uint4*)&Ws[(u ^ (row & 7)) * 8] = pk;
  }
  __syncthreads();

  ffrag acc[8];
#pragma unroll
  for (int oc = 0; oc < 8; oc++) acc[oc] = (ffrag){0.f, 0.f, 0.f, 0.f};

#pragma unroll
  for (int kt = 0; kt < 4; kt++) {
    const float4 x0 = px[kt * 2];
    const float4 x1 = px[kt * 2 + 1];
    bfrag a;
    a[0] = (short)f2bf(x0.x); a[1] = (short)f2bf(x0.y);
    a[2] = (short)f2bf(x0.z); a[3] = (short)f2bf(x0.w);
    a[4] = (short)f2bf(x1.x); a[5] = (short)f2bf(x1.y);
    a[6] = (short)f2bf(x1.z); a[7] = (short)f2bf(x1.w);
#pragma unroll
    for (int oc = 0; oc < 8; oc++) {
      const int u = ((oc * 16 + lr) << 4) + kt * 4 + lg;
      const bfrag b = *(const bfrag*)&Ws[(u ^ (lr & 7)) * 8];
      acc[oc] = __builtin_amdgcn_mfma_f32_16x16x32_bf16(a, b, acc[oc], 0, 0, 0);
    }
  }

  // att-logit epilogue (register-only; before Ws is overwritten)
  float asv[8], adv[8];
#pragma unroll
  for (int oc = 0; oc < 8; oc++) {
    asv[oc] = att_src[oc * 16 + lr];
    adv[oc] = att_dst[oc * 16 + lr];
  }
#pragma unroll
  for (int j = 0; j < 4; j++) {
    float ps[4] = {0.f, 0.f, 0.f, 0.f};
    float pd[4] = {0.f, 0.f, 0.f, 0.f};
#pragma unroll
    for (int oc = 0; oc < 8; oc++) {
      ps[oc >> 1] = fmaf(acc[oc][j], asv[oc], ps[oc >> 1]);
      pd[oc >> 1] = fmaf(acc[oc][j], adv[oc], pd[oc >> 1]);
    }
#pragma unroll
    for (int off = 1; off < 16; off <<= 1) {
#pragma unroll
      for (int hd = 0; hd < 4; hd++) {
        ps[hd] += __shfl_xor(ps[hd], off);
        pd[hd] += __shfl_xor(pd[hd], off);
      }
    }
    int n = nbase + lg * 4 + j;
    if (n < N_NODES && lr < 4) {
      float vs = lr == 0 ? ps[0] : lr == 1 ? ps[1] : lr == 2 ? ps[2] : ps[3];
      float vd = lr == 0 ? pd[0] : lr == 1 ? pd[1] : lr == 2 ? pd[2] : pd[3];
      a_src[n * NH + lr] = vs;
      a_dst[n * NH + lr] = vd;
    }
  }

  // hb store via LDS repack: Ws dead after MFMA loop -> [64][RPS] ushort.
  // Write side ~2-way banks (free); store side fully coalesced dwordx4.
  __syncthreads();   // all waves done reading Ws
#pragma unroll
  for (int oc = 0; oc < 8; oc++) {
#pragma unroll
    for (int j = 0; j < 4; j++) {
      int nl = (wv << 4) + lg * 4 + j;   // local node 0..63
      Ws[nl * RPS + oc * 16 + lr] = f2bf(acc[oc][j]);
    }
  }
  __syncthreads();
#pragma unroll
  for (int r = 0; r < 4; r++) {
    int idx = r * 256 + tid;           // 0..1023
    int nl = idx >> 4, c16 = idx & 15; // node-local, 16B chunk
    int n = gb * 64 + nl;
    if (n < N_NODES)
      *(uint4*)&hb[((size_t)n << 7) + c16 * 8] = *(const uint4*)&Ws[nl * RPS + c16 * 8];
  }
}

// ---------------- K2: per-bucket CSR build (r13 proven) ----------
__global__ __launch_bounds__(256) void binB_kernel(
    const uint_t* __restrict__ ebuf, const int* __restrict__ gcur,
    int* __restrict__ rs, int* __restrict__ re, int* __restrict__ col) {
  __shared__ int cnt[BSZ * NCHUNK];    // 3.3 KB
  __shared__ int roff[BSZ * NCHUNK];
  const int b = blockIdx.x;
  const int tid = threadIdx.x;
  const int n0 = b << 6;
  const int nn = min(BSZ, N_NODES - n0);
  const int s0 = b * CAP;
  const int s1 = s0 + min(gcur[b], CAP);
  for (int k = tid; k < BSZ * NCHUNK; k += 256) cnt[k] = 0;
  __syncthreads();
  for (int i = s0 + tid; i < s1; i += 256) {
    uint_t p = ebuf[i];
    int key = (int)(p >> 24) * NCHUNK + (int)((p & 0xFFFFFFu) >> 12);
    atomicAdd(&cnt[key], 1);
  }
  __syncthreads();
  if (tid < BSZ) {   // one wave: node = tid
    int pref[NCHUNK];
    int tot = 0;
#pragma unroll
    for (int k = 0; k < NCHUNK; k++) { pref[k] = tot; tot += cnt[tid * NCHUNK + k]; }
    int xx = tot;
#pragma unroll
    for (int off = 1; off < 64; off <<= 1) {
      int y = __shfl_up(xx, off, 64);
      if (tid >= off) xx += y;
    }
    const int nodebase = xx - tot;   // exclusive
#pragma unroll
    for (int k = 0; k < NCHUNK; k++) roff[tid * NCHUNK + k] = nodebase + pref[k];
    if (tid < nn) {
      rs[n0 + tid] = s0 + nodebase;
      re[n0 + tid] = s0 + nodebase + tot;
    }
  }
  __syncthreads();
  for (int k = tid; k < BSZ * NCHUNK; k += 256) cnt[k] = 0;
  __syncthreads();
  for (int i = s0 + tid; i < s1; i += 256) {
    uint_t p = ebuf[i];
    int si = (int)(p & 0xFFFFFFu);
    int key = (int)(p >> 24) * NCHUNK + (si >> 12);
    int pos = atomicAdd(&cnt[key], 1);
    int q = s0 + roff[key] + pos;
    if (q >= 0 && q < NBUCK * CAP) col[q] = si;
  }
}

// ---------------- K3: SINGLE-PASS aggregation (r13 proven) ----------------
// out = (sum e_i*h_i)/s + sum h_i,  e_i = exp(leaky(alpha_i)), s = sum e_i.
#define NPB 16
#define CH  16

__global__ __launch_bounds__(256, 8) void agg_kernel(
    const int* __restrict__ col, const int* __restrict__ rs,
    const int* __restrict__ re, const ushort_t* __restrict__ hb,
    const float* __restrict__ a_src, const float* __restrict__ a_dst,
    float* __restrict__ out) {
  __shared__ float w_lds[NPB][CH][NH];   // 4 KB (unnormalized e)
  __shared__ int   si_lds[NPB][CH];      // 1 KB
  const int tid  = threadIdx.x;
  const int slot = tid >> 4;
  const int t    = tid & 15;
  const int node = blockIdx.x * NPB + slot;   // 3125*16 == N_NODES exactly
  const int start = rs[node];
  const int deg   = re[node] - start;
  const float4 ad = *(const float4*)(a_dst + (size_t)node * NH);

  const int head = t >> 2;
  const int c8 = t << 3;
  const ushort_t* hc = hb + c8;
  float s = 0.f;
  float a0 = 0.f, a1 = 0.f, a2 = 0.f, a3 = 0.f;
  float a4 = 0.f, a5 = 0.f, a6 = 0.f, a7 = 0.f;
  float b0 = 0.f, b1 = 0.f, b2 = 0.f, b3 = 0.f;
  float b4 = 0.f, b5 = 0.f, b6 = 0.f, b7 = 0.f;

  for (int base_e = 0; base_e < deg; base_e += CH) {
    int nch = deg - base_e;
    if (nch > CH) nch = CH;
    if (t < nch) {
      int si = col[start + base_e + t];
      si = si < N_NODES ? si : 0;    // defensive clamp
      si_lds[slot][t] = si;
      float4 as = *(const float4*)(a_src + (size_t)si * NH);
      float v0 = as.x + ad.x; v0 = v0 > 0.f ? v0 : 0.2f * v0;
      float v1 = as.y + ad.y; v1 = v1 > 0.f ? v1 : 0.2f * v1;
      float v2 = as.z + ad.z; v2 = v2 > 0.f ? v2 : 0.2f * v2;
      float v3 = as.w + ad.w; v3 = v3 > 0.f ? v3 : 0.2f * v3;
      w_lds[slot][t][0] = __expf(v0);
      w_lds[slot][t][1] = __expf(v1);
      w_lds[slot][t][2] = __expf(v2);
      w_lds[slot][t][3] = __expf(v3);
    }
    __builtin_amdgcn_fence(__ATOMIC_ACQ_REL, "wavefront");
#pragma unroll 2
    for (int j = 0; j < nch; j++) {
      int si = si_lds[slot][j];
      float e = w_lds[slot][j][head];
      s += e;
      const uint4 hv = *(const uint4*)(hc + ((size_t)si << 7));
      float h0 = bf_lo(hv.x), h1 = bf_hi(hv.x);
      float h2 = bf_lo(hv.y), h3 = bf_hi(hv.y);
      float h4 = bf_lo(hv.z), h5 = bf_hi(hv.z);
      float h6 = bf_lo(hv.w), h7 = bf_hi(hv.w);
      a0 = fmaf(h0, e, a0); b0 += h0;
      a1 = fmaf(h1, e, a1); b1 += h1;
      a2 = fmaf(h2, e, a2); b2 += h2;
      a3 = fmaf(h3, e, a3); b3 += h3;
      a4 = fmaf(h4, e, a4); b4 += h4;
      a5 = fmaf(h5, e, a5); b5 += h5;
      a6 = fmaf(h6, e, a6); b6 += h6;
      a7 = fmaf(h7, e, a7); b7 += h7;
    }
    __builtin_amdgcn_fence(__ATOMIC_ACQ_REL, "wavefront");
  }
  const float inv = 1.0f / s;
  float* op = out + ((size_t)node << 7) + c8;
  *(float4*)(op)     = make_float4(fmaf(a0, inv, b0), fmaf(a1, inv, b1),
                                   fmaf(a2, inv, b2), fmaf(a3, inv, b3));
  *(float4*)(op + 4) = make_float4(fmaf(a4, inv, b4), fmaf(a5, inv, b5),
                                   fmaf(a6, inv, b6), fmaf(a7, inv, b7));
}

extern "C" void kernel_launch(void* const* d_in, const int* in_sizes, int n_in,
                              void* d_out, int out_size, void* d_ws, size_t ws_size,
                              hipStream_t stream) {
  const float* x       = (const float*)d_in[0];
  const int*   ei      = (const int*)d_in[1];
  const float* W       = (const float*)d_in[2];
  const float* att_src = (const float*)d_in[3];
  const float* att_dst = (const float*)d_in[4];
  float* out = (float*)d_out;

  // ws: hb | a_src | a_dst | gcur | rs | re | col | ebuf   (~30 MB)
  ushort_t* hb = (ushort_t*)d_ws;
  float* a_src = (float*)(hb + (size_t)N_NODES * DOUT);
  float* a_dst = a_src + (size_t)N_NODES * NH;
  int* gcur    = (int*)(a_dst + (size_t)N_NODES * NH);    // NBUCK
  int* rs      = gcur + NBUCK;                            // N_NODES
  int* re      = rs + N_NODES;                            // N_NODES
  int* col     = re + N_NODES;                            // NBUCK*CAP
  uint_t* ebuf = (uint_t*)(col + (size_t)NBUCK * CAP);    // NBUCK*CAP

  hipMemsetAsync(gcur, 0, (size_t)NBUCK * sizeof(int), stream);

  const int gemm_blocks = (N_NODES + 63) / 64;   // 782
  fused_binA_gemm_kernel<<<NBLK_A + gemm_blocks, 256, 0, stream>>>(
      ei, gcur, ebuf, x, W, att_src, att_dst, hb, a_src, a_dst);
  binB_kernel<<<NBUCK, 256, 0, stream>>>(ebuf, gcur, rs, re, col);
  agg_kernel<<<N_NODES / NPB, 256, 0, stream>>>(col, rs, re, hb, a_src, a_dst, out);
}